// Round 1
// 1021.556 us; speedup vs baseline: 1.0074x; 1.0074x over previous
//
#include <hip/hip_runtime.h>

// Problem constants (B=2, H=16, S=2048, D=64, NUM_EMB=8192)
#define BH     32
#define S_LEN  2048
#define D_DIM  64
#define LDSTR  72      // LDS row stride in halves (64 + 8 pad -> 144B, breaks bank aliasing)

typedef _Float16 half8 __attribute__((ext_vector_type(8)));
typedef _Float16 half4 __attribute__((ext_vector_type(4)));
typedef float    f32x4 __attribute__((ext_vector_type(4)));

// out[b,h,i,j] = scores[b,h,i,j] + sum_d q[b,h,i,d] * emb[j-i+4096, d]
//
// ALIGNED-OUTPUT tiling: block = (bh, ti, tj) owns the aligned 64x64 output tile
// i in [64*ti, 64*ti+64), j in [64*tj, 64*tj+64).  Needed emb rows:
// u = j-i in [j0-i0-63, j0-i0+63]  -> stage 128 rows starting rb = j0-i0+4032
// (rb always in [2048, 6016], rb+127 <= 6143 — no emb bounds checks).
//
// Compute TWO skewed 64x64 MFMA passes over E halves h=0,1: C_h[ii][e] =
// sum_d Q[i0+ii][d] * E[h*64+e][d], which lands at output column
// jj = ii + (h*64+e) - 64.  Exactly one (h,e) hits each jj in [0,64);
// elements with jj outside [0,64) are masked.  MFMA count doubles (free at
// 1.8% MfmaUtil) in exchange for ALL score loads / out stores being aligned
// 64B lane-segments whose 128B lines are completed within a single block
// (same L2) -> no partial-line RMW at HBM.
__global__ __launch_bounds__(256, 4)
void relpos_mfma_kernel(const float* __restrict__ q,
                        const float* __restrict__ sc,
                        const float* __restrict__ emb,
                        float* __restrict__ out)
{
    __shared__ _Float16 Alds[64  * LDSTR];   // Q tile, f16
    __shared__ _Float16 Elds[128 * LDSTR];   // emb tile (128 rows), f16

    const int tid = threadIdx.x;
    int bid = blockIdx.x;
    const int tj = bid & 31;  bid >>= 5;
    const int ti = bid & 31;  bid >>= 5;
    const int bh = bid;
    const int i0 = ti * 64;
    const int j0 = tj * 64;
    const int rb = j0 - i0 + 4032;          // first staged emb row, in [2048,6016]

    // ---- stage Q (64 rows) and E (128 rows) tiles (fp32 -> f16), coalesced ----
    const float* qbase = q   + ((size_t)bh * S_LEN + i0) * D_DIM;
    const float* ebase = emb + (size_t)rb * D_DIM;
    #pragma unroll
    for (int k = 0; k < 4; ++k) {
        int f   = tid + k * 256;            // float4 index 0..1023
        int row = f >> 4;                   // 16 float4 per 64-elem row
        int c4  = (f & 15) * 4;
        f32x4 v = *(const f32x4*)(qbase + row * D_DIM + c4);
        half4 h;
        h.x = (_Float16)v.x; h.y = (_Float16)v.y;
        h.z = (_Float16)v.z; h.w = (_Float16)v.w;
        *(half4*)&Alds[row * LDSTR + c4] = h;
    }
    #pragma unroll
    for (int k = 0; k < 8; ++k) {
        int f   = tid + k * 256;            // float4 index 0..2047
        int row = f >> 4;                   // 128 rows
        int c4  = (f & 15) * 4;
        f32x4 v = *(const f32x4*)(ebase + row * D_DIM + c4);
        half4 h;
        h.x = (_Float16)v.x; h.y = (_Float16)v.y;
        h.z = (_Float16)v.z; h.w = (_Float16)v.w;
        *(half4*)&Elds[row * LDSTR + c4] = h;
    }
    __syncthreads();

    const int wave = tid >> 6;     // 4 waves: output rows [16w, 16w+16)
    const int lane = tid & 63;
    const int lrow = lane & 15;
    const int quad = lane >> 4;
    const int ii_base = wave * 16 + quad * 4;

    // ---- prefetch scores directly into the MFMA C-operand (aligned segments) ----
    // C/D layout (16x16x32): col = lane&15 (+16c), row = quad*4 + reg (+16w)
    const unsigned tbase = ((unsigned)(bh * S_LEN + i0)) * (unsigned)S_LEN + (unsigned)j0;
    f32x4 acc[2][4];
    #pragma unroll
    for (int h = 0; h < 2; ++h) {
        #pragma unroll
        for (int c = 0; c < 4; ++c) {
            int uu = c * 16 + lrow;
            #pragma unroll
            for (int r = 0; r < 4; ++r) {
                int ii = ii_base + r;
                int jj = ii + h * 64 + uu - 64;     // output column within tile
                bool v = (unsigned)jj < 64u;
                acc[h][c][r] = v ? sc[tbase + (unsigned)(ii * S_LEN + jj)] : 0.0f;
            }
        }
    }

    // ---- fragments + MFMA: acc[h][c] += A * E_half ----
    // A-frag: A[m=lane&15][k=quad*8+j]; B-frag: B[k][n=lane&15] = E[n][k]
    const _Float16* arow = &Alds[(wave * 16 + lrow) * LDSTR + quad * 8];
    half8 a0 = *(const half8*)(arow);        // k in [0,32)
    half8 a1 = *(const half8*)(arow + 32);   // k in [32,64)

    #pragma unroll
    for (int h = 0; h < 2; ++h) {
        #pragma unroll
        for (int c = 0; c < 4; ++c) {
            const _Float16* brow = &Elds[(h * 64 + c * 16 + lrow) * LDSTR + quad * 8];
            half8 b0 = *(const half8*)(brow);
            half8 b1 = *(const half8*)(brow + 32);
            acc[h][c] = __builtin_amdgcn_mfma_f32_16x16x32_f16(a0, b0, acc[h][c], 0, 0, 0);
            acc[h][c] = __builtin_amdgcn_mfma_f32_16x16x32_f16(a1, b1, acc[h][c], 0, 0, 0);
        }
    }

    // ---- epilogue: store masked (aligned 64B lane-segments, lines completed in-block) ----
    #pragma unroll
    for (int h = 0; h < 2; ++h) {
        #pragma unroll
        for (int c = 0; c < 4; ++c) {
            int uu = c * 16 + lrow;
            #pragma unroll
            for (int r = 0; r < 4; ++r) {
                int ii = ii_base + r;
                int jj = ii + h * 64 + uu - 64;
                if ((unsigned)jj < 64u) {
                    out[tbase + (unsigned)(ii * S_LEN + jj)] = acc[h][c][r];
                }
            }
        }
    }
}

extern "C" void kernel_launch(void* const* d_in, const int* in_sizes, int n_in,
                              void* d_out, int out_size, void* d_ws, size_t ws_size,
                              hipStream_t stream) {
    const float* q   = (const float*)d_in[0];   // [B,H,S,D] fp32
    const float* sc  = (const float*)d_in[1];   // [B,H,S,S] fp32
    const float* emb = (const float*)d_in[2];   // [NUM_EMB,D] fp32
    float* out = (float*)d_out;                 // [B,H,S,S] fp32

    dim3 grid(BH * 32 * 32);   // 32,768 blocks, one aligned 64x64 output tile each
    relpos_mfma_kernel<<<grid, 256, 0, stream>>>(q, sc, emb, out);
}

// Round 2
// 962.784 us; speedup vs baseline: 1.0689x; 1.0610x over previous
//
#include <hip/hip_runtime.h>

// Problem constants (B=2, H=16, S=2048, D=64, NUM_EMB=8192)
#define S_LEN  2048
#define D_DIM  64
#define LDSTR  72      // LDS row stride in halves (64 + 8 pad -> 144B, breaks bank aliasing)

typedef _Float16 half8 __attribute__((ext_vector_type(8)));
typedef _Float16 half4 __attribute__((ext_vector_type(4)));
typedef float    f32x4 __attribute__((ext_vector_type(4)));

// out[b,h,i,j] = scores[b,h,i,j] + sum_d q[b,h,i,d] * emb[j-i+4096, d]
//
// Persistent-row blocks: block = (bh, ti) owns output rows i in [64*ti, +64)
// and sweeps tj = 0..31 (aligned 64x64 tiles).  Q fragments live in registers
// for the whole sweep.  E window for tile tj = emb rows [64*(tj-ti)+4032, +128)
// slides by 64/step -> 3-slot x 64-row LDS ring: compute on chunks {tj, tj+1},
// prefetch chunk tj+2 into the third slot (disjoint -> ONE barrier per step).
// Two skewed MFMA passes h=0,1: element (ii, e=c*16+lrow) of pass h lands at
// output column jj = ii + h*64 + e - 64; each jj in [0,64) hit exactly once.
// Scores for tile tj+1 are issued right after the MFMAs consume tile tj's ->
// in flight across stores + ds_write + barrier.  All score/out accesses are
// aligned segments; output cache lines completed within one block (one L2).
__global__ __launch_bounds__(256, 4)
void relpos_row_kernel(const float* __restrict__ q,
                       const float* __restrict__ sc,
                       const float* __restrict__ emb,
                       float* __restrict__ out)
{
    __shared__ _Float16 Elds[3][64 * LDSTR];   // E ring, f16

    const int tid = threadIdx.x;
    const int ti  = blockIdx.x & 31;
    const int bh  = blockIdx.x >> 5;
    const int i0  = ti * 64;

    const int wave = tid >> 6;     // 4 waves: output rows [16w, 16w+16)
    const int lane = tid & 63;
    const int lrow = lane & 15;
    const int quad = lane >> 4;
    const int ii_base = wave * 16 + quad * 4;

    // staging geometry: 64 rows x 16 float4 per chunk, 4 float4 per thread
    const int srow = tid >> 4;          // base row 0..15 (+16 per k)
    const int scol = (tid & 15) * 4;    // float column

    // chunk n (n in [0,32]) = emb rows [64*n + 4032 - i0, +64); always in [2048,6143]
    const float* embase = emb + (size_t)(4032 - i0) * D_DIM;

    // ---- prologue: issue chunk0 + chunk1 loads ----
    f32x4 er0[4], er1[4];
    {
        const float* e0 = embase;
        const float* e1 = embase + 64 * D_DIM;
        #pragma unroll
        for (int k = 0; k < 4; ++k) {
            er0[k] = *(const f32x4*)(e0 + (srow + k * 16) * D_DIM + scol);
            er1[k] = *(const f32x4*)(e1 + (srow + k * 16) * D_DIM + scol);
        }
    }

    // ---- Q fragments straight from global (fp32 -> f16), one-time ----
    // A-frag: A[m=lrow][k=quad*8+j], halves at k+0 / k+32; rows offset by wave*16
    half8 a0, a1;
    {
        const float* qrow = q + (size_t)(bh * S_LEN + i0 + wave * 16 + lrow) * D_DIM + quad * 8;
        f32x4 v0 = *(const f32x4*)(qrow);
        f32x4 v1 = *(const f32x4*)(qrow + 4);
        f32x4 v2 = *(const f32x4*)(qrow + 32);
        f32x4 v3 = *(const f32x4*)(qrow + 36);
        a0[0] = (_Float16)v0.x; a0[1] = (_Float16)v0.y; a0[2] = (_Float16)v0.z; a0[3] = (_Float16)v0.w;
        a0[4] = (_Float16)v1.x; a0[5] = (_Float16)v1.y; a0[6] = (_Float16)v1.z; a0[7] = (_Float16)v1.w;
        a1[0] = (_Float16)v2.x; a1[1] = (_Float16)v2.y; a1[2] = (_Float16)v2.z; a1[3] = (_Float16)v2.w;
        a1[4] = (_Float16)v3.x; a1[5] = (_Float16)v3.y; a1[6] = (_Float16)v3.z; a1[7] = (_Float16)v3.w;
    }

    // ---- preload scores for tj=0 into the MFMA accumulator ----
    // C/D layout (16x16x32): col = lane&15 (+16c), row = quad*4 + reg (+16w)
    const unsigned tb0 = ((unsigned)(bh * S_LEN + i0)) * (unsigned)S_LEN;
    f32x4 acc[2][4];
    #pragma unroll
    for (int h = 0; h < 2; ++h) {
        #pragma unroll
        for (int c = 0; c < 4; ++c) {
            const int uu = h * 64 + c * 16 + lrow;
            #pragma unroll
            for (int r = 0; r < 4; ++r) {
                const int ii = ii_base + r;
                const int jj = ii + uu - 64;
                acc[h][c][r] = ((unsigned)jj < 64u)
                             ? sc[tb0 + (unsigned)(ii * S_LEN + jj)] : 0.0f;
            }
        }
    }

    // ---- write chunks 0,1 into ring slots 0,1 ----
    #pragma unroll
    for (int k = 0; k < 4; ++k) {
        half4 h0, h1;
        h0.x = (_Float16)er0[k].x; h0.y = (_Float16)er0[k].y;
        h0.z = (_Float16)er0[k].z; h0.w = (_Float16)er0[k].w;
        h1.x = (_Float16)er1[k].x; h1.y = (_Float16)er1[k].y;
        h1.z = (_Float16)er1[k].z; h1.w = (_Float16)er1[k].w;
        *(half4*)&Elds[0][(srow + k * 16) * LDSTR + scol] = h0;
        *(half4*)&Elds[1][(srow + k * 16) * LDSTR + scol] = h1;
    }
    __syncthreads();

    for (int tj = 0; tj < 32; ++tj) {
        // 1. issue next-chunk global loads (chunk tj+2 -> slot (tj+2)%3)
        f32x4 er[4];
        const bool pf = (tj <= 30);
        if (pf) {
            const float* en = embase + (size_t)(tj + 2) * 64 * D_DIM;
            #pragma unroll
            for (int k = 0; k < 4; ++k)
                er[k] = *(const f32x4*)(en + (srow + k * 16) * D_DIM + scol);
        }

        // 2. MFMA on window chunks {tj, tj+1} (slots disjoint from write slot)
        const int s0 = tj % 3;
        const int s1 = (tj + 1) % 3;
        #pragma unroll
        for (int h = 0; h < 2; ++h) {
            const _Float16* bb = Elds[h ? s1 : s0];
            #pragma unroll
            for (int c = 0; c < 4; ++c) {
                const _Float16* brow = bb + (c * 16 + lrow) * LDSTR + quad * 8;
                half8 b0 = *(const half8*)(brow);
                half8 b1 = *(const half8*)(brow + 32);
                acc[h][c] = __builtin_amdgcn_mfma_f32_16x16x32_f16(a0, b0, acc[h][c], 0, 0, 0);
                acc[h][c] = __builtin_amdgcn_mfma_f32_16x16x32_f16(a1, b1, acc[h][c], 0, 0, 0);
            }
        }

        // 3. store tile tj (aligned 64B lane-segments)
        const unsigned tb = tb0 + (unsigned)(tj * 64);
        #pragma unroll
        for (int h = 0; h < 2; ++h) {
            #pragma unroll
            for (int c = 0; c < 4; ++c) {
                const int uu = h * 64 + c * 16 + lrow;
                #pragma unroll
                for (int r = 0; r < 4; ++r) {
                    const int ii = ii_base + r;
                    const int jj = ii + uu - 64;
                    if ((unsigned)jj < 64u)
                        out[tb + (unsigned)(ii * S_LEN + jj)] = acc[h][c][r];
                }
            }
        }

        // 4. reload scores for tile tj+1 (in flight across ds_write + barrier)
        if (tj < 31) {
            const unsigned tbn = tb + 64;
            #pragma unroll
            for (int h = 0; h < 2; ++h) {
                #pragma unroll
                for (int c = 0; c < 4; ++c) {
                    const int uu = h * 64 + c * 16 + lrow;
                    #pragma unroll
                    for (int r = 0; r < 4; ++r) {
                        const int ii = ii_base + r;
                        const int jj = ii + uu - 64;
                        acc[h][c][r] = ((unsigned)jj < 64u)
                                     ? sc[tbn + (unsigned)(ii * S_LEN + jj)] : 0.0f;
                    }
                }
            }
        }

        // 5. write prefetched chunk into its ring slot (nobody reads it this step)
        if (pf) {
            _Float16* dst = Elds[(tj + 2) % 3];
            #pragma unroll
            for (int k = 0; k < 4; ++k) {
                half4 hh;
                hh.x = (_Float16)er[k].x; hh.y = (_Float16)er[k].y;
                hh.z = (_Float16)er[k].z; hh.w = (_Float16)er[k].w;
                *(half4*)&dst[(srow + k * 16) * LDSTR + scol] = hh;
            }
        }
        __syncthreads();
    }
}

extern "C" void kernel_launch(void* const* d_in, const int* in_sizes, int n_in,
                              void* d_out, int out_size, void* d_ws, size_t ws_size,
                              hipStream_t stream) {
    const float* q   = (const float*)d_in[0];   // [B,H,S,D] fp32
    const float* sc  = (const float*)d_in[1];   // [B,H,S,S] fp32
    const float* emb = (const float*)d_in[2];   // [NUM_EMB,D] fp32
    float* out = (float*)d_out;                 // [B,H,S,S] fp32

    dim3 grid(32 * 32);   // (bh, ti): 1024 persistent row-blocks = 4 per CU
    relpos_row_kernel<<<grid, 256, 0, stream>>>(q, sc, emb, out);
}